// Round 9
// baseline (206.307 us; speedup 1.0000x reference)
//
#include <hip/hip_runtime.h>

// SpatialGridProjector: out[b,q,j,i] = sum_k trilinear(density[b], P(i,j,k))
// X(k) = Ax + k*R20, Y(k) = Ay + k*R21, Z(k) = Az + k*R22  (voxel coords)
// grid_sample(align_corners=True, zero padding).
//
// R12 = R11 + per-pose lane-transpose. R11 post-mortem: VALU cut (40->35.8%
// busy, VGPR 32->24) moved proj only 128->126.5us => NOT issue-bound; with
// warm-replay evidence (same time, ~0 HBM) the limiter is TA/L1 cache-line
// serialization of the 64-lane gathers. A wave's lanes can run along i
// (motion (R00,R01,R02)/pixel) or j ((R10,R11,R12)/pixel); lines touched
// scale with the y/z components. Pick per pose (block-uniform) the direction
// with larger |x-component|: T = |R10|>|R00| -> lanes along j. Rescues the
// worst poses (|R00|~0). Store becomes stride-512B once per ray (amortized).
// Everything else frozen: 2048x256, XCD swizzle, 4-stage interior, 2-stage
// boundary, f16 y-pair + v_dot2_f32_f16.

#define LSZ 128
#define PACKED_BYTES ((size_t)4 * 128 * 128 * 128 * 8)  // 64 MiB

typedef unsigned int u4v __attribute__((ext_vector_type(4), aligned(8)));
typedef _Float16 h2 __attribute__((ext_vector_type(2)));

__device__ __forceinline__ h2 ash2(unsigned int u) {
    union { unsigned int u; h2 h; } c; c.u = u; return c.h;
}
__device__ __forceinline__ float dot2(unsigned int pair, h2 w, float acc) {
    return __builtin_amdgcn_fdot2(ash2(pair), w, acc, false);
}
__device__ __forceinline__ h2 pkw(float lo, float hi) {
    auto t = __builtin_amdgcn_cvt_pkrtz(lo, hi);
    union { decltype(t) a; h2 b; } c; c.a = t; return c.b;
}
__device__ __forceinline__ unsigned int pkh(float lo, float hi) {
    auto t = __builtin_amdgcn_cvt_pkrtz(lo, hi);
    union { decltype(t) a; unsigned int u; } c; c.a = t; return c.u;
}

// ---------------- pack kernel: f32 volume -> corner-packed f16 --------------
// entry (z,y,x): dword0 = f16{ v(z,y,x), v(z,y+1,x) }
//               dword1 = f16{ v(z+1,y,x), v(z+1,y+1,x) }
__global__ __launch_bounds__(256) void pack_kernel(
    const float* __restrict__ density, uint2* __restrict__ packed)
{
    const int t  = blockIdx.x * 256 + threadIdx.x;
    const int xq = (t & 31) << 2;          // x quad base
    const int y  = (t >> 5) & 127;
    const int z  = (t >> 12) & 127;
    const int b  = t >> 19;
    const float* __restrict__ v = density + ((size_t)b << 21);
    const int y1 = min(y + 1, 127), z1 = min(z + 1, 127);
    const float4 a0 = *(const float4*)(v + (z  << 14) + (y  << 7) + xq);
    const float4 a1 = *(const float4*)(v + (z  << 14) + (y1 << 7) + xq);
    const float4 c0 = *(const float4*)(v + (z1 << 14) + (y  << 7) + xq);
    const float4 c1 = *(const float4*)(v + (z1 << 14) + (y1 << 7) + xq);
    uint4 o0, o1;
    o0.x = pkh(a0.x, a1.x); o0.y = pkh(c0.x, c1.x);
    o0.z = pkh(a0.y, a1.y); o0.w = pkh(c0.y, c1.y);
    o1.x = pkh(a0.z, a1.z); o1.y = pkh(c0.z, c1.z);
    o1.z = pkh(a0.w, a1.w); o1.w = pkh(c0.w, c1.w);
    uint4* dst = (uint4*)(packed + ((size_t)b << 21) + (z << 14) + (y << 7) + xq);
    dst[0] = o0; dst[1] = o1;
}

// ---------------- interior fast path (all corners valid) --------------------
// Stage carry: u (4 dwords), hy (packed y-weights), fx, fz.
#define FPREPI(S, kk) do {                                                    \
    const float kf_ = (float)min((kk), d);                                    \
    const float X_ = fmaf(kf_, R20, Ax);                                      \
    const float Y_ = fmaf(kf_, R21, Ay);                                      \
    const float Z_ = fmaf(kf_, R22, Az);                                      \
    const int ix_ = (int)X_;                                                  \
    const int iy_ = (int)Y_;                                                  \
    const int iz_ = (int)Z_;                                                  \
    fx##S = __builtin_amdgcn_fractf(X_);                                      \
    const float fy_ = __builtin_amdgcn_fractf(Y_);                            \
    fz##S = __builtin_amdgcn_fractf(Z_);                                      \
    hy##S = pkw(1.0f - fy_, fy_);                                             \
    u##S = *(const u4v*)(vol2 + ((iz_ << 14) + (iy_ << 7) + ix_));            \
} while (0)

#define FCONSI(S) do {                                                        \
    const float gx0 = 1.0f - fx##S;                                           \
    const float gz0 = 1.0f - fz##S;                                           \
    const float m00 = dot2(u##S.x, hy##S, 0.0f);  /* (x0,z0) */               \
    const float m01 = dot2(u##S.y, hy##S, 0.0f);  /* (x0,z1) */               \
    const float m10 = dot2(u##S.z, hy##S, 0.0f);  /* (x1,z0) */               \
    const float m11 = dot2(u##S.w, hy##S, 0.0f);  /* (x1,z1) */               \
    const float s0_ = fmaf(gx0, m00, fx##S * m10);                            \
    const float s1_ = fmaf(gx0, m01, fx##S * m11);                            \
    acc = fmaf(gz0, s0_, fmaf(fz##S, s1_, acc));                              \
} while (0)

// ---------------- boundary safe path (clamped + selects) --------------------
#define SPREP(S, kk) do {                                                     \
    const float kf_ = (float)(kk);                                            \
    const float X_ = fmaf(kf_, R20, Ax);                                      \
    const float Y_ = fmaf(kf_, R21, Ay);                                      \
    const float Z_ = fmaf(kf_, R22, Az);                                      \
    const int ix_ = (int)floorf(X_);                                          \
    const int iy_ = (int)floorf(Y_);                                          \
    const int iz_ = (int)floorf(Z_);                                          \
    const int ex_ = min(max(ix_, 0), 126);                                    \
    const int ey_ = min(max(iy_, 0), 126);                                    \
    const int ez_ = min(max(iz_, 0), 126);                                    \
    u##S = *(const u4v*)(vol2 + ((ez_ << 14) + (ey_ << 7) + ex_));            \
} while (0)

// y-clamp handled by weight-slot selection (pair at ey holds {v(ey),v(ey+1)}):
//   normal: {gy0, gy1};  iy==-1: {gy1, 0};  iy==127: {0, gy0}
#define SCONS(S, kk) do {                                                     \
    const float kf_ = (float)(kk);                                            \
    const float X_ = fmaf(kf_, R20, Ax);                                      \
    const float Y_ = fmaf(kf_, R21, Ay);                                      \
    const float Z_ = fmaf(kf_, R22, Az);                                      \
    const float xf_ = floorf(X_), yf_ = floorf(Y_), zf_ = floorf(Z_);         \
    const int ix_ = (int)xf_, iy_ = (int)yf_, iz_ = (int)zf_;                 \
    const float fx_ = X_ - xf_, fy_ = Y_ - yf_, fz_ = Z_ - zf_;               \
    const bool vx0_ = (ix_ >= 0)  & (ix_ <= 127);                             \
    const bool vx1_ = (ix_ >= -1) & (ix_ <= 126);                             \
    const bool vy0_ = (iy_ >= 0)  & (iy_ <= 127);                             \
    const bool vy1_ = (iy_ >= -1) & (iy_ <= 126);                             \
    const bool vz0_ = (iz_ >= 0)  & (iz_ <= 127);                             \
    const bool vz1_ = (iz_ >= -1) & (iz_ <= 126);                             \
    const float gx0 = vx0_ ? (1.0f - fx_) : 0.0f;                             \
    const float gx1 = vx1_ ? fx_ : 0.0f;                                      \
    const float gy0 = vy0_ ? (1.0f - fy_) : 0.0f;                             \
    const float gy1 = vy1_ ? fy_ : 0.0f;                                      \
    const float gz0 = vz0_ ? (1.0f - fz_) : 0.0f;                             \
    const float gz1 = vz1_ ? fz_ : 0.0f;                                      \
    const bool xhi_ = (ix_ > 126), xlo_ = (ix_ < 0);                          \
    const bool yhi_ = (iy_ > 126), ylo_ = (iy_ < 0);                          \
    const bool zhi_ = (iz_ > 126), zlo_ = (iz_ < 0);                          \
    const float wlo_ = ylo_ ? gy1 : (yhi_ ? 0.0f : gy0);                      \
    const float whi_ = yhi_ ? gy0 : (ylo_ ? 0.0f : gy1);                      \
    const h2 hy_ = pkw(wlo_, whi_);                                           \
    const unsigned int a0z0 = xhi_ ? u##S.z : u##S.x;                         \
    const unsigned int a0z1 = xhi_ ? u##S.w : u##S.y;                         \
    const unsigned int a1z0 = xlo_ ? u##S.x : u##S.z;                         \
    const unsigned int a1z1 = xlo_ ? u##S.y : u##S.w;                         \
    const unsigned int dA = zhi_ ? a0z1 : a0z0;  /* (x0,z0) */                \
    const unsigned int dB = zlo_ ? a0z0 : a0z1;  /* (x0,z1) */                \
    const unsigned int dC = zhi_ ? a1z1 : a1z0;  /* (x1,z0) */                \
    const unsigned int dD = zlo_ ? a1z0 : a1z1;  /* (x1,z1) */                \
    const float m00 = dot2(dA, hy_, 0.0f);                                    \
    const float m01 = dot2(dB, hy_, 0.0f);                                    \
    const float m10 = dot2(dC, hy_, 0.0f);                                    \
    const float m11 = dot2(dD, hy_, 0.0f);                                    \
    const float s0_ = fmaf(gx0, m00, gx1 * m10);                              \
    const float s1_ = fmaf(gx0, m01, gx1 * m11);                              \
    acc = fmaf(gz0, s0_, fmaf(gz1, s1_, acc));                                \
} while (0)

__global__ __launch_bounds__(256) void proj_kernel_packed(
    const uint2* __restrict__ packed,    // (B, L, L, L) corner-packed f16
    const float* __restrict__ rotation,  // (B, Q, 3, 3)
    float* __restrict__ out)             // (B, Q, L, L)
{
    // XCD-aware swizzle: volume b -> XCDs {2b, 2b+1} (blockIdx % 8 ~ XCD).
    const int xcd  = blockIdx.x & 7;
    const int slot = blockIdx.x >> 3;
    const int b    = xcd >> 1;
    const int tile = ((xcd & 1) << 8) + slot;
    const int q    = tile >> 6;
    const int blk  = tile & 63;
    const int bq   = (b << 3) + q;

    const float* R = rotation + bq * 9;
    const float R00 = R[0], R01 = R[1], R02 = R[2];
    const float R10 = R[3], R11 = R[4], R12 = R[5];
    const float R20 = R[6], R21 = R[7], R22 = R[8];

    // Per-pose lane-transpose (block-uniform): lanes run along the screen
    // direction whose motion vector has the larger |x| component -> fewer
    // distinct 64B lines per wave gather.
    const bool T = fabsf(R10) > fabsf(R00);
    const int p = (blk << 8) + threadIdx.x;
    const int i = T ? (p >> 7) : (p & 127);
    const int j = T ? (p & 127) : (p >> 7);

    const float step = 2.0f / 127.0f;
    const float li = -1.0f + (float)i * step;
    const float lj = -1.0f + (float)j * step;

    const float Ax = 63.5f * (li * R00 + lj * R10 - R20 + 1.0f);
    const float Ay = 63.5f * (li * R01 + lj * R11 - R21 + 1.0f);
    const float Az = 63.5f * (li * R02 + lj * R12 - R22 + 1.0f);

    // outer interval: A + k*s in (-1, 128) per axis
    float klo = 0.0f, khi = 127.0f;
    // interior interval: A + k*s in [0, 126.95] per axis (all corners valid)
    float klo2 = 0.0f, khi2 = 127.0f;
    bool empty = false, empty2 = false;
    {
        const float a_[3] = {Ax, Ay, Az};
        const float s_[3] = {R20, R21, R22};
        #pragma unroll
        for (int m = 0; m < 3; ++m) {
            if (fabsf(s_[m]) > 1e-6f) {
                const float r = 1.0f / s_[m];
                const float t0 = (-1.0f   - a_[m]) * r;
                const float t1 = (128.0f  - a_[m]) * r;
                klo = fmaxf(klo, fminf(t0, t1));
                khi = fminf(khi, fmaxf(t0, t1));
                const float w0 = (0.0f    - a_[m]) * r;
                const float w1 = (126.95f - a_[m]) * r;
                klo2 = fmaxf(klo2, fminf(w0, w1));
                khi2 = fminf(khi2, fmaxf(w0, w1));
            } else {
                if (a_[m] <= -1.0f   || a_[m] >= 128.0f)   empty  = true;
                if (a_[m] <  0.001f  || a_[m] >  126.94f)  empty2 = true;
            }
        }
    }
    int a = (int)ceilf(klo - 1e-3f);
    int bnd = (int)floorf(khi + 1e-3f);
    if (a < 0) a = 0;
    if (bnd > 127) bnd = 127;
    if (empty) bnd = a - 1;

    int c = (int)ceilf(klo2 + 0.05f);
    int d = (int)floorf(khi2 - 0.05f);
    if (c < a) c = a;
    if (d > bnd) d = bnd;
    if (empty2 || d < c) { c = bnd + 1; d = bnd; }

    const uint2* __restrict__ vol2 = packed + ((size_t)b << 21);

    float acc = 0.0f;
    u4v uA, uB, uC, uD;
    h2 hyA, hyB, hyC, hyD;
    float fxA, fzA, fxB, fzB, fxC, fzC, fxD, fzD;
    (void)hyA; (void)fxA; (void)fzA;  // boundary path uses uA/uB only

    // ---- boundary head: [a, c-1], 2-stage safe pipeline ----
    {
        int k = a;
        const int e = c - 1;
        if (k <= e) {
            SPREP(A, k);
            while (k <= e) {
                const int kn = k + 1;
                const bool hasB = (kn <= e);
                if (hasB) SPREP(B, kn);
                SCONS(A, k);
                if (hasB) SCONS(B, kn);
                k += 2;
                if (k <= e) SPREP(A, k);
            }
        }
    }

    // ---- interior: [c, d], 4-stage fast pipeline (no clamps/selects) ----
    {
        int n = d - c + 1;
        int k = c;
        if (n > 0) {
            FPREPI(A, k); FPREPI(B, k + 1); FPREPI(C, k + 2);
            while (n > 0) {
                FPREPI(D, k + 3);
                FCONSI(A);
                FPREPI(A, k + 4);
                if (n > 1) FCONSI(B);
                FPREPI(B, k + 5);
                if (n > 2) FCONSI(C);
                FPREPI(C, k + 6);
                if (n > 3) FCONSI(D);
                k += 4; n -= 4;
            }
        }
    }

    // ---- boundary tail: [d+1, bnd], 2-stage safe pipeline ----
    {
        int k = d + 1;
        const int e = bnd;
        if (k <= e) {
            SPREP(A, k);
            while (k <= e) {
                const int kn = k + 1;
                const bool hasB = (kn <= e);
                if (hasB) SPREP(B, kn);
                SCONS(A, k);
                if (hasB) SCONS(B, kn);
                k += 2;
                if (k <= e) SPREP(A, k);
            }
        }
    }

    out[(bq << 14) + (j << 7) + i] = acc;
}

// ---------------- fallback (R4-style, f32 pair loads) if ws too small -------
__global__ __launch_bounds__(256) void proj_kernel_fallback(
    const float* __restrict__ density,
    const float* __restrict__ rotation,
    float* __restrict__ out)
{
    const int xcd  = blockIdx.x & 7;
    const int slot = blockIdx.x >> 3;
    const int b    = xcd >> 1;
    const int tile = ((xcd & 1) << 8) + slot;
    const int q    = tile >> 6;
    const int blk  = tile & 63;
    const int bq   = (b << 3) + q;

    const int p = (blk << 8) + threadIdx.x;
    const int i = p & (LSZ - 1);
    const int j = p >> 7;

    const float* R = rotation + bq * 9;
    const float R00 = R[0], R01 = R[1], R02 = R[2];
    const float R10 = R[3], R11 = R[4], R12 = R[5];
    const float R20 = R[6], R21 = R[7], R22 = R[8];

    const float step = 2.0f / 127.0f;
    const float li = -1.0f + (float)i * step;
    const float lj = -1.0f + (float)j * step;

    const float Ax = 63.5f * (li * R00 + lj * R10 - R20 + 1.0f);
    const float Ay = 63.5f * (li * R01 + lj * R11 - R21 + 1.0f);
    const float Az = 63.5f * (li * R02 + lj * R12 - R22 + 1.0f);

    float klo = 0.0f, khi = 127.0f;
    bool empty = false;
    {
        const float a_[3] = {Ax, Ay, Az};
        const float s_[3] = {R20, R21, R22};
        #pragma unroll
        for (int m = 0; m < 3; ++m) {
            if (fabsf(s_[m]) > 1e-6f) {
                const float t0 = (-1.0f  - a_[m]) / s_[m];
                const float t1 = (128.0f - a_[m]) / s_[m];
                klo = fmaxf(klo, fminf(t0, t1));
                khi = fminf(khi, fmaxf(t0, t1));
            } else if (a_[m] <= -1.0f || a_[m] >= 128.0f) {
                empty = true;
            }
        }
    }
    int k_start = (int)ceilf(klo - 1e-3f);
    int k_end   = (int)floorf(khi + 1e-3f);
    if (k_start < 0) k_start = 0;
    if (k_end > 127) k_end = 127;
    if (empty) k_end = k_start - 1;

    const float* __restrict__ vol = density + (size_t)b * (LSZ * LSZ * LSZ);

    float acc = 0.0f;
    for (int k = k_start; k <= k_end; ++k) {
        const float kf = (float)k;
        const float X = fmaf(kf, R20, Ax);
        const float Y = fmaf(kf, R21, Ay);
        const float Z = fmaf(kf, R22, Az);
        const float xf = floorf(X), yf = floorf(Y), zf = floorf(Z);
        const int ix = (int)xf, iy = (int)yf, iz = (int)zf;
        const float fx = X - xf, fy = Y - yf, fz = Z - zf;
        const bool vx0 = (ix >= 0)  & (ix <= 127);
        const bool vx1 = (ix >= -1) & (ix <= 126);
        const bool vy0 = (iy >= 0)  & (iy <= 127);
        const bool vy1 = (iy >= -1) & (iy <= 126);
        const bool vz0 = (iz >= 0)  & (iz <= 127);
        const bool vz1 = (iz >= -1) & (iz <= 126);
        const int cx0 = min(max(ix, 0), 127);
        const int cx1 = min(max(ix + 1, 0), 127);
        const int cy0 = min(max(iy, 0), 127);
        const int cy1 = min(max(iy + 1, 0), 127);
        const int cz0 = min(max(iz, 0), 127);
        const int cz1 = min(max(iz + 1, 0), 127);
        const float gx0 = vx0 ? (1.0f - fx) : 0.0f;
        const float gx1 = vx1 ? fx : 0.0f;
        const float gy0 = vy0 ? (1.0f - fy) : 0.0f;
        const float gy1 = vy1 ? fy : 0.0f;
        const float gz0 = vz0 ? (1.0f - fz) : 0.0f;
        const float gz1 = vz1 ? fz : 0.0f;
        const int z0o = cz0 << 14, z1o = cz1 << 14;
        const int y0o = cy0 << 7,  y1o = cy1 << 7;
        const float v000 = vol[z0o + y0o + cx0];
        const float v100 = vol[z0o + y0o + cx1];
        const float v010 = vol[z0o + y1o + cx0];
        const float v110 = vol[z0o + y1o + cx1];
        const float v001 = vol[z1o + y0o + cx0];
        const float v101 = vol[z1o + y0o + cx1];
        const float v011 = vol[z1o + y1o + cx0];
        const float v111 = vol[z1o + y1o + cx1];
        const float s0 = gy0 * fmaf(gx0, v000, gx1 * v100)
                       + gy1 * fmaf(gx0, v010, gx1 * v110);
        const float s1 = gy0 * fmaf(gx0, v001, gx1 * v101)
                       + gy1 * fmaf(gx0, v011, gx1 * v111);
        acc = fmaf(gz0, s0, fmaf(gz1, s1, acc));
    }

    out[(bq << 14) + p] = acc;
}

extern "C" void kernel_launch(void* const* d_in, const int* in_sizes, int n_in,
                              void* d_out, int out_size, void* d_ws, size_t ws_size,
                              hipStream_t stream) {
    const float* density  = (const float*)d_in[0];
    const float* rotation = (const float*)d_in[1];
    float* out = (float*)d_out;

    if (ws_size >= PACKED_BYTES) {
        uint2* packed = (uint2*)d_ws;
        pack_kernel<<<8192, 256, 0, stream>>>(density, packed);
        proj_kernel_packed<<<2048, 256, 0, stream>>>(packed, rotation, out);
    } else {
        proj_kernel_fallback<<<2048, 256, 0, stream>>>(density, rotation, out);
    }
}

// Round 11
// 205.465 us; speedup vs baseline: 1.0041x; 1.0041x over previous
//
#include <hip/hip_runtime.h>

// SpatialGridProjector: out[b,q,j,i] = sum_k trilinear(density[b], P(i,j,k))
// X(k) = Ax + k*R20, Y(k) = Ay + k*R21, Z(k) = Az + k*R22  (voxel coords)
// grid_sample(align_corners=True, zero padding).
//
// R13 (resubmitted after infra timeout) = R11 proj (best: 126.5us) +
// z-marching pack.
//  - R12 post-mortem: lane-transpose neutral-to-worse (lines/gather are set
//    by distinct (y,z) rows across lanes, saturating at ~64 for Gaussian
//    rotations regardless of lane direction; stores lost coalescing).
//    proj reverted to R11 verbatim.
//  - The stable ~79us gap between total (205.8) and proj (126.5) is pack +
//    overhead, vs a 15-25us pack roofline (32MB read + 64MB write). Old pack:
//    4 float4 loads per output quad (4x read amplification via y+1/z+1
//    neighbors), 4 entries/thread, zero load pipelining. New pack: thread
//    owns (xq,y), marches z-chunk of 8 carrying previous slice rows in
//    registers -> 2.25 loads/quad, 8-deep unrolled loop for MLP.
//    1024 blocks x 256 thr = 16 waves/CU.

#define LSZ 128
#define PACKED_BYTES ((size_t)4 * 128 * 128 * 128 * 8)  // 64 MiB

typedef unsigned int u4v __attribute__((ext_vector_type(4), aligned(8)));
typedef _Float16 h2 __attribute__((ext_vector_type(2)));

__device__ __forceinline__ h2 ash2(unsigned int u) {
    union { unsigned int u; h2 h; } c; c.u = u; return c.h;
}
__device__ __forceinline__ float dot2(unsigned int pair, h2 w, float acc) {
    return __builtin_amdgcn_fdot2(ash2(pair), w, acc, false);
}
__device__ __forceinline__ h2 pkw(float lo, float hi) {
    auto t = __builtin_amdgcn_cvt_pkrtz(lo, hi);
    union { decltype(t) a; h2 b; } c; c.a = t; return c.b;
}
__device__ __forceinline__ unsigned int pkh(float lo, float hi) {
    auto t = __builtin_amdgcn_cvt_pkrtz(lo, hi);
    union { decltype(t) a; unsigned int u; } c; c.a = t; return c.u;
}

// ---------------- pack kernel v2: z-marching f32 -> corner-packed f16 -------
// entry (z,y,x): dword0 = f16{ v(z,y,x), v(z,y+1,x) }
//               dword1 = f16{ v(z+1,y,x), v(z+1,y+1,x) }
// Thread owns (b, zchunk of 8, y, xq); marches z carrying prev slice rows.
__global__ __launch_bounds__(256) void pack_kernel(
    const float* __restrict__ density, uint2* __restrict__ packed)
{
    const int t  = blockIdx.x * 256 + threadIdx.x;
    const int xq = (t & 31) << 2;          // x quad base
    const int y  = (t >> 5) & 127;
    const int zc = (t >> 12) & 15;         // z chunk (8 slices each)
    const int b  = t >> 16;
    const float* __restrict__ v = density + ((size_t)b << 21);
    const int y1 = min(y + 1, 127);
    const int z0 = zc << 3;

    float4 a0 = *(const float4*)(v + (z0 << 14) + (y  << 7) + xq);
    float4 a1 = *(const float4*)(v + (z0 << 14) + (y1 << 7) + xq);
    uint2* __restrict__ dst =
        packed + ((size_t)b << 21) + (z0 << 14) + (y << 7) + xq;

    #pragma unroll
    for (int dz = 0; dz < 8; ++dz) {
        const int zn = min(z0 + dz + 1, 127);
        const float4 c0 = *(const float4*)(v + (zn << 14) + (y  << 7) + xq);
        const float4 c1 = *(const float4*)(v + (zn << 14) + (y1 << 7) + xq);
        uint4 o0, o1;
        o0.x = pkh(a0.x, a1.x); o0.y = pkh(c0.x, c1.x);
        o0.z = pkh(a0.y, a1.y); o0.w = pkh(c0.y, c1.y);
        o1.x = pkh(a0.z, a1.z); o1.y = pkh(c0.z, c1.z);
        o1.z = pkh(a0.w, a1.w); o1.w = pkh(c0.w, c1.w);
        uint4* d4 = (uint4*)dst;
        d4[0] = o0; d4[1] = o1;
        dst += (1 << 14);
        a0 = c0; a1 = c1;
    }
}

// ---------------- interior fast path (all corners valid) --------------------
// Stage carry: u (4 dwords), hy (packed y-weights), fx, fz.
#define FPREPI(S, kk) do {                                                    \
    const float kf_ = (float)min((kk), d);                                    \
    const float X_ = fmaf(kf_, R20, Ax);                                      \
    const float Y_ = fmaf(kf_, R21, Ay);                                      \
    const float Z_ = fmaf(kf_, R22, Az);                                      \
    const int ix_ = (int)X_;                                                  \
    const int iy_ = (int)Y_;                                                  \
    const int iz_ = (int)Z_;                                                  \
    fx##S = __builtin_amdgcn_fractf(X_);                                      \
    const float fy_ = __builtin_amdgcn_fractf(Y_);                            \
    fz##S = __builtin_amdgcn_fractf(Z_);                                      \
    hy##S = pkw(1.0f - fy_, fy_);                                             \
    u##S = *(const u4v*)(vol2 + ((iz_ << 14) + (iy_ << 7) + ix_));            \
} while (0)

#define FCONSI(S) do {                                                        \
    const float gx0 = 1.0f - fx##S;                                           \
    const float gz0 = 1.0f - fz##S;                                           \
    const float m00 = dot2(u##S.x, hy##S, 0.0f);  /* (x0,z0) */               \
    const float m01 = dot2(u##S.y, hy##S, 0.0f);  /* (x0,z1) */               \
    const float m10 = dot2(u##S.z, hy##S, 0.0f);  /* (x1,z0) */               \
    const float m11 = dot2(u##S.w, hy##S, 0.0f);  /* (x1,z1) */               \
    const float s0_ = fmaf(gx0, m00, fx##S * m10);                            \
    const float s1_ = fmaf(gx0, m01, fx##S * m11);                            \
    acc = fmaf(gz0, s0_, fmaf(fz##S, s1_, acc));                              \
} while (0)

// ---------------- boundary safe path (clamped + selects) --------------------
#define SPREP(S, kk) do {                                                     \
    const float kf_ = (float)(kk);                                            \
    const float X_ = fmaf(kf_, R20, Ax);                                      \
    const float Y_ = fmaf(kf_, R21, Ay);                                      \
    const float Z_ = fmaf(kf_, R22, Az);                                      \
    const int ix_ = (int)floorf(X_);                                          \
    const int iy_ = (int)floorf(Y_);                                          \
    const int iz_ = (int)floorf(Z_);                                          \
    const int ex_ = min(max(ix_, 0), 126);                                    \
    const int ey_ = min(max(iy_, 0), 126);                                    \
    const int ez_ = min(max(iz_, 0), 126);                                    \
    u##S = *(const u4v*)(vol2 + ((ez_ << 14) + (ey_ << 7) + ex_));            \
} while (0)

// y-clamp handled by weight-slot selection (pair at ey holds {v(ey),v(ey+1)}):
//   normal: {gy0, gy1};  iy==-1: {gy1, 0};  iy==127: {0, gy0}
#define SCONS(S, kk) do {                                                     \
    const float kf_ = (float)(kk);                                            \
    const float X_ = fmaf(kf_, R20, Ax);                                      \
    const float Y_ = fmaf(kf_, R21, Ay);                                      \
    const float Z_ = fmaf(kf_, R22, Az);                                      \
    const float xf_ = floorf(X_), yf_ = floorf(Y_), zf_ = floorf(Z_);         \
    const int ix_ = (int)xf_, iy_ = (int)yf_, iz_ = (int)zf_;                 \
    const float fx_ = X_ - xf_, fy_ = Y_ - yf_, fz_ = Z_ - zf_;               \
    const bool vx0_ = (ix_ >= 0)  & (ix_ <= 127);                             \
    const bool vx1_ = (ix_ >= -1) & (ix_ <= 126);                             \
    const bool vy0_ = (iy_ >= 0)  & (iy_ <= 127);                             \
    const bool vy1_ = (iy_ >= -1) & (iy_ <= 126);                             \
    const bool vz0_ = (iz_ >= 0)  & (iz_ <= 127);                             \
    const bool vz1_ = (iz_ >= -1) & (iz_ <= 126);                             \
    const float gx0 = vx0_ ? (1.0f - fx_) : 0.0f;                             \
    const float gx1 = vx1_ ? fx_ : 0.0f;                                      \
    const float gy0 = vy0_ ? (1.0f - fy_) : 0.0f;                             \
    const float gy1 = vy1_ ? fy_ : 0.0f;                                      \
    const float gz0 = vz0_ ? (1.0f - fz_) : 0.0f;                             \
    const float gz1 = vz1_ ? fz_ : 0.0f;                                      \
    const bool xhi_ = (ix_ > 126), xlo_ = (ix_ < 0);                          \
    const bool yhi_ = (iy_ > 126), ylo_ = (iy_ < 0);                          \
    const bool zhi_ = (iz_ > 126), zlo_ = (iz_ < 0);                          \
    const float wlo_ = ylo_ ? gy1 : (yhi_ ? 0.0f : gy0);                      \
    const float whi_ = yhi_ ? gy0 : (ylo_ ? 0.0f : gy1);                      \
    const h2 hy_ = pkw(wlo_, whi_);                                           \
    const unsigned int a0z0 = xhi_ ? u##S.z : u##S.x;                         \
    const unsigned int a0z1 = xhi_ ? u##S.w : u##S.y;                         \
    const unsigned int a1z0 = xlo_ ? u##S.x : u##S.z;                         \
    const unsigned int a1z1 = xlo_ ? u##S.y : u##S.w;                         \
    const unsigned int dA = zhi_ ? a0z1 : a0z0;  /* (x0,z0) */                \
    const unsigned int dB = zlo_ ? a0z0 : a0z1;  /* (x0,z1) */                \
    const unsigned int dC = zhi_ ? a1z1 : a1z0;  /* (x1,z0) */                \
    const unsigned int dD = zlo_ ? a1z0 : a1z1;  /* (x1,z1) */                \
    const float m00 = dot2(dA, hy_, 0.0f);                                    \
    const float m01 = dot2(dB, hy_, 0.0f);                                    \
    const float m10 = dot2(dC, hy_, 0.0f);                                    \
    const float m11 = dot2(dD, hy_, 0.0f);                                    \
    const float s0_ = fmaf(gx0, m00, gx1 * m10);                              \
    const float s1_ = fmaf(gx0, m01, gx1 * m11);                              \
    acc = fmaf(gz0, s0_, fmaf(gz1, s1_, acc));                                \
} while (0)

__global__ __launch_bounds__(256) void proj_kernel_packed(
    const uint2* __restrict__ packed,    // (B, L, L, L) corner-packed f16
    const float* __restrict__ rotation,  // (B, Q, 3, 3)
    float* __restrict__ out)             // (B, Q, L, L)
{
    // XCD-aware swizzle: volume b -> XCDs {2b, 2b+1} (blockIdx % 8 ~ XCD).
    const int xcd  = blockIdx.x & 7;
    const int slot = blockIdx.x >> 3;
    const int b    = xcd >> 1;
    const int tile = ((xcd & 1) << 8) + slot;
    const int q    = tile >> 6;
    const int blk  = tile & 63;
    const int bq   = (b << 3) + q;

    const int p = (blk << 8) + threadIdx.x;
    const int i = p & (LSZ - 1);
    const int j = p >> 7;

    const float* R = rotation + bq * 9;
    const float R00 = R[0], R01 = R[1], R02 = R[2];
    const float R10 = R[3], R11 = R[4], R12 = R[5];
    const float R20 = R[6], R21 = R[7], R22 = R[8];

    const float step = 2.0f / 127.0f;
    const float li = -1.0f + (float)i * step;
    const float lj = -1.0f + (float)j * step;

    const float Ax = 63.5f * (li * R00 + lj * R10 - R20 + 1.0f);
    const float Ay = 63.5f * (li * R01 + lj * R11 - R21 + 1.0f);
    const float Az = 63.5f * (li * R02 + lj * R12 - R22 + 1.0f);

    // outer interval: A + k*s in (-1, 128) per axis
    float klo = 0.0f, khi = 127.0f;
    // interior interval: A + k*s in [0, 126.95] per axis (all corners valid)
    float klo2 = 0.0f, khi2 = 127.0f;
    bool empty = false, empty2 = false;
    {
        const float a_[3] = {Ax, Ay, Az};
        const float s_[3] = {R20, R21, R22};
        #pragma unroll
        for (int m = 0; m < 3; ++m) {
            if (fabsf(s_[m]) > 1e-6f) {
                const float r = 1.0f / s_[m];
                const float t0 = (-1.0f   - a_[m]) * r;
                const float t1 = (128.0f  - a_[m]) * r;
                klo = fmaxf(klo, fminf(t0, t1));
                khi = fminf(khi, fmaxf(t0, t1));
                const float w0 = (0.0f    - a_[m]) * r;
                const float w1 = (126.95f - a_[m]) * r;
                klo2 = fmaxf(klo2, fminf(w0, w1));
                khi2 = fminf(khi2, fmaxf(w0, w1));
            } else {
                if (a_[m] <= -1.0f   || a_[m] >= 128.0f)   empty  = true;
                if (a_[m] <  0.001f  || a_[m] >  126.94f)  empty2 = true;
            }
        }
    }
    int a = (int)ceilf(klo - 1e-3f);
    int bnd = (int)floorf(khi + 1e-3f);
    if (a < 0) a = 0;
    if (bnd > 127) bnd = 127;
    if (empty) bnd = a - 1;

    int c = (int)ceilf(klo2 + 0.05f);
    int d = (int)floorf(khi2 - 0.05f);
    if (c < a) c = a;
    if (d > bnd) d = bnd;
    if (empty2 || d < c) { c = bnd + 1; d = bnd; }

    const uint2* __restrict__ vol2 = packed + ((size_t)b << 21);

    float acc = 0.0f;
    u4v uA, uB, uC, uD;
    h2 hyA, hyB, hyC, hyD;
    float fxA, fzA, fxB, fzB, fxC, fzC, fxD, fzD;
    (void)hyA; (void)fxA; (void)fzA;  // boundary path uses uA/uB only

    // ---- boundary head: [a, c-1], 2-stage safe pipeline ----
    {
        int k = a;
        const int e = c - 1;
        if (k <= e) {
            SPREP(A, k);
            while (k <= e) {
                const int kn = k + 1;
                const bool hasB = (kn <= e);
                if (hasB) SPREP(B, kn);
                SCONS(A, k);
                if (hasB) SCONS(B, kn);
                k += 2;
                if (k <= e) SPREP(A, k);
            }
        }
    }

    // ---- interior: [c, d], 4-stage fast pipeline (no clamps/selects) ----
    {
        int n = d - c + 1;
        int k = c;
        if (n > 0) {
            FPREPI(A, k); FPREPI(B, k + 1); FPREPI(C, k + 2);
            while (n > 0) {
                FPREPI(D, k + 3);
                FCONSI(A);
                FPREPI(A, k + 4);
                if (n > 1) FCONSI(B);
                FPREPI(B, k + 5);
                if (n > 2) FCONSI(C);
                FPREPI(C, k + 6);
                if (n > 3) FCONSI(D);
                k += 4; n -= 4;
            }
        }
    }

    // ---- boundary tail: [d+1, bnd], 2-stage safe pipeline ----
    {
        int k = d + 1;
        const int e = bnd;
        if (k <= e) {
            SPREP(A, k);
            while (k <= e) {
                const int kn = k + 1;
                const bool hasB = (kn <= e);
                if (hasB) SPREP(B, kn);
                SCONS(A, k);
                if (hasB) SCONS(B, kn);
                k += 2;
                if (k <= e) SPREP(A, k);
            }
        }
    }

    out[(bq << 14) + p] = acc;
}

// ---------------- fallback (R4-style, f32 pair loads) if ws too small -------
__global__ __launch_bounds__(256) void proj_kernel_fallback(
    const float* __restrict__ density,
    const float* __restrict__ rotation,
    float* __restrict__ out)
{
    const int xcd  = blockIdx.x & 7;
    const int slot = blockIdx.x >> 3;
    const int b    = xcd >> 1;
    const int tile = ((xcd & 1) << 8) + slot;
    const int q    = tile >> 6;
    const int blk  = tile & 63;
    const int bq   = (b << 3) + q;

    const int p = (blk << 8) + threadIdx.x;
    const int i = p & (LSZ - 1);
    const int j = p >> 7;

    const float* R = rotation + bq * 9;
    const float R00 = R[0], R01 = R[1], R02 = R[2];
    const float R10 = R[3], R11 = R[4], R12 = R[5];
    const float R20 = R[6], R21 = R[7], R22 = R[8];

    const float step = 2.0f / 127.0f;
    const float li = -1.0f + (float)i * step;
    const float lj = -1.0f + (float)j * step;

    const float Ax = 63.5f * (li * R00 + lj * R10 - R20 + 1.0f);
    const float Ay = 63.5f * (li * R01 + lj * R11 - R21 + 1.0f);
    const float Az = 63.5f * (li * R02 + lj * R12 - R22 + 1.0f);

    float klo = 0.0f, khi = 127.0f;
    bool empty = false;
    {
        const float a_[3] = {Ax, Ay, Az};
        const float s_[3] = {R20, R21, R22};
        #pragma unroll
        for (int m = 0; m < 3; ++m) {
            if (fabsf(s_[m]) > 1e-6f) {
                const float t0 = (-1.0f  - a_[m]) / s_[m];
                const float t1 = (128.0f - a_[m]) / s_[m];
                klo = fmaxf(klo, fminf(t0, t1));
                khi = fminf(khi, fmaxf(t0, t1));
            } else if (a_[m] <= -1.0f || a_[m] >= 128.0f) {
                empty = true;
            }
        }
    }
    int k_start = (int)ceilf(klo - 1e-3f);
    int k_end   = (int)floorf(khi + 1e-3f);
    if (k_start < 0) k_start = 0;
    if (k_end > 127) k_end = 127;
    if (empty) k_end = k_start - 1;

    const float* __restrict__ vol = density + (size_t)b * (LSZ * LSZ * LSZ);

    float acc = 0.0f;
    for (int k = k_start; k <= k_end; ++k) {
        const float kf = (float)k;
        const float X = fmaf(kf, R20, Ax);
        const float Y = fmaf(kf, R21, Ay);
        const float Z = fmaf(kf, R22, Az);
        const float xf = floorf(X), yf = floorf(Y), zf = floorf(Z);
        const int ix = (int)xf, iy = (int)yf, iz = (int)zf;
        const float fx = X - xf, fy = Y - yf, fz = Z - zf;
        const bool vx0 = (ix >= 0)  & (ix <= 127);
        const bool vx1 = (ix >= -1) & (ix <= 126);
        const bool vy0 = (iy >= 0)  & (iy <= 127);
        const bool vy1 = (iy >= -1) & (iy <= 126);
        const bool vz0 = (iz >= 0)  & (iz <= 127);
        const bool vz1 = (iz >= -1) & (iz <= 126);
        const int cx0 = min(max(ix, 0), 127);
        const int cx1 = min(max(ix + 1, 0), 127);
        const int cy0 = min(max(iy, 0), 127);
        const int cy1 = min(max(iy + 1, 0), 127);
        const int cz0 = min(max(iz, 0), 127);
        const int cz1 = min(max(iz + 1, 0), 127);
        const float gx0 = vx0 ? (1.0f - fx) : 0.0f;
        const float gx1 = vx1 ? fx : 0.0f;
        const float gy0 = vy0 ? (1.0f - fy) : 0.0f;
        const float gy1 = vy1 ? fy : 0.0f;
        const float gz0 = vz0 ? (1.0f - fz) : 0.0f;
        const float gz1 = vz1 ? fz : 0.0f;
        const int z0o = cz0 << 14, z1o = cz1 << 14;
        const int y0o = cy0 << 7,  y1o = cy1 << 7;
        const float v000 = vol[z0o + y0o + cx0];
        const float v100 = vol[z0o + y0o + cx1];
        const float v010 = vol[z0o + y1o + cx0];
        const float v110 = vol[z0o + y1o + cx1];
        const float v001 = vol[z1o + y0o + cx0];
        const float v101 = vol[z1o + y0o + cx1];
        const float v011 = vol[z1o + y1o + cx0];
        const float v111 = vol[z1o + y1o + cx1];
        const float s0 = gy0 * fmaf(gx0, v000, gx1 * v100)
                       + gy1 * fmaf(gx0, v010, gx1 * v110);
        const float s1 = gy0 * fmaf(gx0, v001, gx1 * v101)
                       + gy1 * fmaf(gx0, v011, gx1 * v111);
        acc = fmaf(gz0, s0, fmaf(gz1, s1, acc));
    }

    out[(bq << 14) + p] = acc;
}

extern "C" void kernel_launch(void* const* d_in, const int* in_sizes, int n_in,
                              void* d_out, int out_size, void* d_ws, size_t ws_size,
                              hipStream_t stream) {
    const float* density  = (const float*)d_in[0];
    const float* rotation = (const float*)d_in[1];
    float* out = (float*)d_out;

    if (ws_size >= PACKED_BYTES) {
        uint2* packed = (uint2*)d_ws;
        pack_kernel<<<1024, 256, 0, stream>>>(density, packed);
        proj_kernel_packed<<<2048, 256, 0, stream>>>(packed, rotation, out);
    } else {
        proj_kernel_fallback<<<2048, 256, 0, stream>>>(density, rotation, out);
    }
}